// Round 8
// baseline (129.467 us; speedup 1.0000x reference)
//
#include <hip/hip_runtime.h>
#include <cmath>

#define B_ 2
#define X_ 128
#define Y_ 128
#define Z_ 128
#define C_ 8
#define ZC 1024         // Z_*C_
#define ZC4 256         // ZC/4
#define XS 131072       // Y_*ZC, stride of x in elements
#define BS 16777216     // X_*XS, stride of batch in elements
#define PF4 32768       // float4s per (b,x) plane = XS/4
#define KTAPS 13
#define TAIL 6

struct Taps { float k[KTAPS]; };

__device__ __forceinline__ float4 ld4(const float* p) {
    return *reinterpret_cast<const float4*>(p);
}
__device__ __forceinline__ void st4(float* p, const float4& v) {
    *reinterpret_cast<float4*>(p) = v;
}
__device__ __forceinline__ float4 f4zero() { return make_float4(0.f, 0.f, 0.f, 0.f); }
__device__ __forceinline__ void fma4(float4& a, float s, const float4& b) {
    a.x = fmaf(s, b.x, a.x); a.y = fmaf(s, b.y, a.y);
    a.z = fmaf(s, b.z, a.z); a.w = fmaf(s, b.w, a.w);
}

// -------- Pass 2: conv along X, gather, running against L3-warm tmp ----------
// R3-R7 established: the 512KB-strided plane-gather against DRAM caps at
// ~2.9 TB/s regardless of occupancy (57%), MLP (28/wave, ~300KB/CU in
// flight), or per-visit granularity (8KB): each plane-visit gives each HBM
// channel only ~one 256B burst per row-activate. Fix is structural: run this
// pass SECOND so `src` (= tmp, just written by the contiguous pass) is
// L3-resident -- SRAM has no activate penalty for strided reads. f-chunk
// order is reversed so the first blocks here read the last-written tmp.
template <int W>
__global__ __launch_bounds__(256, 1) void xconv_gather(const float* __restrict__ src,
                                                       float* __restrict__ dst,
                                                       Taps tp) {
    const int gid = blockIdx.x;
    const int fc  = (PF4 / 256 - 1) - (gid & (PF4 / 256 - 1));  // reversed
    const int xw  = (gid >> 7) & (X_ / W - 1);      // 8 x-windows (W=16)
    const int b   = gid >> 10;

    const int f4   = fc * 256 + threadIdx.x;        // float4 index in plane
    const int x0   = xw * W;
    const int base = b * BS + (f4 << 2);

    float4 v[W + 2 * TAIL];
#pragma unroll
    for (int i = 0; i < W + 2 * TAIL; ++i) {
        const int xx = x0 - TAIL + i;
        v[i] = (xx >= 0 && xx < X_) ? ld4(src + base + xx * XS) : f4zero();
    }
    // Pin all 28 float4 live (each load must precede its pin)...
#pragma unroll
    for (int i = 0; i < W + 2 * TAIL; ++i) {
        asm volatile("" : "+v"(v[i].x), "+v"(v[i].y), "+v"(v[i].z), "+v"(v[i].w));
    }
    // ...and forbid any instruction (incl. register-only FMAs) from crossing.
    __builtin_amdgcn_sched_barrier(0);

#pragma unroll
    for (int j = 0; j < W; ++j) {
        float4 acc = f4zero();
#pragma unroll
        for (int i = 0; i < KTAPS; ++i) fma4(acc, tp.k[i], v[j + i]);
        st4(dst + base + (x0 + j) * XS, acc);
    }
}

// ------------- Pass 1: fused conv along Y (registers) + Z (LDS row) ----------
// Block = 256 threads covering one full (z,c) row (1024 floats as float4s) of
// one (b,x) plane; slides along a Y segment. Y-result row -> LDS
// (double-buffered); Z-conv reads 13 z-neighbors from that LDS row and writes
// tmp. Loads march contiguously (+4KB/iter) -> ~5.2 TB/s measured.
template <int SEGY>
__global__ __launch_bounds__(256) void yzconv_kernel(const float* __restrict__ src,
                                                     float* __restrict__ dst,
                                                     Taps tp) {
    __shared__ float row[2][ZC];

    const int t  = threadIdx.x;           // 0..255
    const int x  = blockIdx.x & (X_ - 1);
    int rest     = blockIdx.x >> 7;
    const int b  = rest & (B_ - 1);
    const int s  = rest >> 1;

    const int pbase = b * BS + x * XS;    // plane base
    const int zc    = t << 2;             // word offset in row, float4-aligned
    const int z     = t >> 1;
    const int cw    = (t & 1) << 2;

    const int ylen = Y_ / SEGY;
    const int y0   = s * ylen;

    float4 w[KTAPS];
#pragma unroll
    for (int i = 0; i < KTAPS - 1; ++i) {
        const int yy = y0 - TAIL + i;
        w[i] = (yy >= 0 && yy < Y_) ? ld4(src + pbase + yy * ZC + zc) : f4zero();
    }
    const int yl = y0 + TAIL;
    float4 nv = (yl < Y_) ? ld4(src + pbase + yl * ZC + zc) : f4zero();

    int p = 0;
    for (int y = y0; y < y0 + ylen; ++y) {
        const int yf = y + TAIL + 1;
        float4 fut = (yf < Y_) ? ld4(src + pbase + yf * ZC + zc) : f4zero();

        // Y conv
        w[KTAPS - 1] = nv;
        float4 acc = f4zero();
#pragma unroll
        for (int i = 0; i < KTAPS; ++i) fma4(acc, tp.k[i], w[i]);
        st4(&row[p][zc], acc);
        __syncthreads();

        // Z conv from LDS (offsets are 4t + 8*(i-6): linear in lane, conflict-free)
        float4 zacc = f4zero();
#pragma unroll
        for (int i = 0; i < KTAPS; ++i) {
            const int zz = z - TAIL + i;
            if (zz >= 0 && zz < Z_) {
                float4 vv = ld4(&row[p][(zz << 3) + cw]);
                fma4(zacc, tp.k[i], vv);
            }
        }
        st4(dst + pbase + y * ZC + zc, zacc);

#pragma unroll
        for (int i = 0; i < KTAPS - 1; ++i) w[i] = w[i + 1];
        nv = fut;
        p ^= 1;
        // single barrier per iter is safe: next write goes to the other buffer,
        // and the write 2 iters later is dominated by the next barrier.
    }
}

extern "C" void kernel_launch(void* const* d_in, const int* in_sizes, int n_in,
                              void* d_out, int out_size, void* d_ws, size_t ws_size,
                              hipStream_t stream) {
    const float* in = (const float*)d_in[0];
    float* out = (float*)d_out;

    // Gaussian taps: tail = int(2.0*3.0 + 0.5) = 6, K = 13, sigma = 2
    Taps tp;
    {
        float kv[KTAPS];
        float sum = 0.f;
        for (int i = 0; i < KTAPS; ++i) {
            const float xx = (float)(i - TAIL);
            kv[i] = expf(-0.5f * xx * xx / 4.0f);
            sum += kv[i];
        }
        for (int i = 0; i < KTAPS; ++i) tp.k[i] = kv[i] / sum;
    }

    const size_t need_bytes = (size_t)B_ * BS * sizeof(float);  // 134 MB
    const bool use_ws = (ws_size >= need_bytes) && (d_ws != nullptr);
    float* tmp = use_ws ? (float*)d_ws : out;

    if (use_ws) {
        // Pass 1: contiguous Y+Z fused conv, in -> tmp (DRAM-friendly stream).
        yzconv_kernel<8><<<B_ * X_ * 8, 256, 0, stream>>>(in, tmp, tp);
        // Pass 2: strided X conv, tmp (L3-warm) -> out.
        xconv_gather<16><<<B_ * (X_ / 16) * (PF4 / 256), 256, 0, stream>>>(tmp, out, tp);
    } else {
        // Fallback without workspace: old order; X gather in->out (distinct
        // buffers), then Y+Z marching conv in-place on out (write lags reads).
        xconv_gather<16><<<B_ * (X_ / 16) * (PF4 / 256), 256, 0, stream>>>(in, out, tp);
        yzconv_kernel<1><<<B_ * X_, 256, 0, stream>>>(out, out, tp);
    }
}

// Round 9
// 122.159 us; speedup vs baseline: 1.0598x; 1.0598x over previous
//
#include <hip/hip_runtime.h>
#include <cmath>

#define B_ 2
#define X_ 128
#define Y_ 128
#define Z_ 128
#define C_ 8
#define ZC 1024         // Z_*C_
#define ZC4 256         // ZC/4
#define XS 131072       // Y_*ZC, stride of x in elements
#define BS 16777216     // X_*XS, stride of batch in elements
#define PF4 32768       // float4s per (b,x) plane = XS/4
#define KTAPS 13
#define TAIL 6

struct Taps { float k[KTAPS]; };

__device__ __forceinline__ float4 ld4(const float* p) {
    return *reinterpret_cast<const float4*>(p);
}
__device__ __forceinline__ void st4(float* p, const float4& v) {
    *reinterpret_cast<float4*>(p) = v;
}
__device__ __forceinline__ float4 f4zero() { return make_float4(0.f, 0.f, 0.f, 0.f); }
__device__ __forceinline__ void fma4(float4& a, float s, const float4& b) {
    a.x = fmaf(s, b.x, a.x); a.y = fmaf(s, b.y, a.y);
    a.z = fmaf(s, b.z, a.z); a.w = fmaf(s, b.w, a.w);
}

// -------- Pass 2: conv along X, gather, running against L3-warm tmp ----------
// R8 measured: this pass on L3-warm src = 33 us (vs 75 us cold). Keep.
template <int W>
__global__ __launch_bounds__(256, 1) void xconv_gather(const float* __restrict__ src,
                                                       float* __restrict__ dst,
                                                       Taps tp) {
    const int gid = blockIdx.x;
    const int fc  = (PF4 / 256 - 1) - (gid & (PF4 / 256 - 1));  // reversed
    const int xw  = (gid >> 7) & (X_ / W - 1);      // 8 x-windows (W=16)
    const int b   = gid >> 10;

    const int f4   = fc * 256 + threadIdx.x;        // float4 index in plane
    const int x0   = xw * W;
    const int base = b * BS + (f4 << 2);

    float4 v[W + 2 * TAIL];
#pragma unroll
    for (int i = 0; i < W + 2 * TAIL; ++i) {
        const int xx = x0 - TAIL + i;
        v[i] = (xx >= 0 && xx < X_) ? ld4(src + base + xx * XS) : f4zero();
    }
#pragma unroll
    for (int i = 0; i < W + 2 * TAIL; ++i) {
        asm volatile("" : "+v"(v[i].x), "+v"(v[i].y), "+v"(v[i].z), "+v"(v[i].w));
    }
    __builtin_amdgcn_sched_barrier(0);

#pragma unroll
    for (int j = 0; j < W; ++j) {
        float4 acc = f4zero();
#pragma unroll
        for (int i = 0; i < KTAPS; ++i) fma4(acc, tp.k[i], v[j + i]);
        st4(dst + base + (x0 + j) * XS, acc);
    }
}

// ------------- Pass 1: fused Y (reg window) + Z (LDS row) conv ---------------
// R8 post-mortem: cold-read version ran at 2.55 TB/s because __syncthreads()
// lowers with a vmcnt(0) drain, killing the depth-1 prefetch each iteration
// -> every y-step paid ~900cy cold-HBM latency serially. This version:
//  * P=4 register prefetch rows per wave (static indices via unroll)
//  * raw s_barrier with manual lgkmcnt(0) (LDS visibility) -- global loads
//    stay in flight ACROSS barriers (counted-vmcnt principle)
//  * s-inner block order: concurrent blocks cover whole 512KB planes densely.
template <int SEGY, int P>
__global__ __launch_bounds__(256) void yzconv_kernel(const float* __restrict__ src,
                                                     float* __restrict__ dst,
                                                     Taps tp) {
    __shared__ float row[2][ZC];

    const int t  = threadIdx.x;                 // 0..255
    const int s  = blockIdx.x & (SEGY - 1);     // s inner: 8 consecutive blocks
    const int x  = (blockIdx.x >> 3) & (X_ - 1);//  cover one full plane densely
    const int b  = blockIdx.x >> 10;

    const int pbase = b * BS + x * XS;    // plane base
    const int zc    = t << 2;             // word offset in row, float4-aligned
    const int z     = t >> 1;
    const int cw    = (t & 1) << 2;

    const int ylen = Y_ / SEGY;
    const int y0   = s * ylen;

    auto ldrow = [&](int yy) -> float4 {
        return (yy >= 0 && yy < Y_) ? ld4(src + pbase + yy * ZC + zc) : f4zero();
    };

    float4 w[KTAPS];
#pragma unroll
    for (int i = 0; i < KTAPS - 1; ++i) w[i] = ldrow(y0 - TAIL + i);

    float4 pf[P];
#pragma unroll
    for (int i = 0; i < P; ++i) pf[i] = ldrow(y0 + TAIL + i);

    int p = 0;
    for (int yy = 0; yy < ylen; yy += P) {
#pragma unroll
        for (int k = 0; k < P; ++k) {          // full unroll: pf[k] static (rule #20)
            const int y = y0 + yy + k;

            // consume prefetched row y+6 (compiler emits counted vmcnt wait)
            w[KTAPS - 1] = pf[k];
            // refill slot with row y+6+P (stays in flight across barriers)
            pf[k] = ldrow(y + TAIL + P);

            // Y conv
            float4 acc = f4zero();
#pragma unroll
            for (int i = 0; i < KTAPS; ++i) fma4(acc, tp.k[i], w[i]);
            st4(&row[p][zc], acc);

            // LDS visibility WITHOUT draining vmcnt: wait ds ops only.
            asm volatile("s_waitcnt lgkmcnt(0)" ::: "memory");
            __builtin_amdgcn_s_barrier();
            __builtin_amdgcn_sched_barrier(0);  // nothing crosses the barrier

            // Z conv from LDS (conflict-free: offsets linear in lane)
            float4 zacc = f4zero();
#pragma unroll
            for (int i = 0; i < KTAPS; ++i) {
                const int zz = z - TAIL + i;
                if (zz >= 0 && zz < Z_) {
                    fma4(zacc, tp.k[i], ld4(&row[p][(zz << 3) + cw]));
                }
            }
            st4(dst + pbase + y * ZC + zc, zacc);

#pragma unroll
            for (int i = 0; i < KTAPS - 1; ++i) w[i] = w[i + 1];
            p ^= 1;
            // safe: wave's own ds_reads complete before its next barrier
            // (lgkmcnt(0)), and buffer re-write is two barriers away.
        }
    }
}

extern "C" void kernel_launch(void* const* d_in, const int* in_sizes, int n_in,
                              void* d_out, int out_size, void* d_ws, size_t ws_size,
                              hipStream_t stream) {
    const float* in = (const float*)d_in[0];
    float* out = (float*)d_out;

    // Gaussian taps: tail = int(2.0*3.0 + 0.5) = 6, K = 13, sigma = 2
    Taps tp;
    {
        float kv[KTAPS];
        float sum = 0.f;
        for (int i = 0; i < KTAPS; ++i) {
            const float xx = (float)(i - TAIL);
            kv[i] = expf(-0.5f * xx * xx / 4.0f);
            sum += kv[i];
        }
        for (int i = 0; i < KTAPS; ++i) tp.k[i] = kv[i] / sum;
    }

    const size_t need_bytes = (size_t)B_ * BS * sizeof(float);  // 134 MB
    const bool use_ws = (ws_size >= need_bytes) && (d_ws != nullptr);
    float* tmp = use_ws ? (float*)d_ws : out;

    if (use_ws) {
        // Pass 1: contiguous Y+Z fused conv, in (cold) -> tmp. Deep prefetch
        // + no-drain barriers keep 4 rows/wave in flight.
        yzconv_kernel<8, 4><<<B_ * X_ * 8, 256, 0, stream>>>(in, tmp, tp);
        // Pass 2: strided X conv, tmp (L3-warm) -> out. Measured 33 us.
        xconv_gather<16><<<B_ * (X_ / 16) * (PF4 / 256), 256, 0, stream>>>(tmp, out, tp);
    } else {
        // Fallback without workspace: X gather in->out (distinct buffers),
        // then Y+Z conv in-place on out (global reads lead writes by >=7 rows).
        xconv_gather<16><<<B_ * (X_ / 16) * (PF4 / 256), 256, 0, stream>>>(in, out, tp);
        yzconv_kernel<1, 4><<<B_ * X_, 256, 0, stream>>>(out, out, tp);
    }
}